// Round 1
// baseline (219.050 us; speedup 1.0000x reference)
//
#include <hip/hip_runtime.h>
#include <stdint.h>

#define Tn 65536
#define Dn 768
#define NSEG 4096   // B*S = 32*128

typedef __bf16 bf16;
typedef __bf16 bf16x8 __attribute__((ext_vector_type(8)));
typedef float f32x4 __attribute__((ext_vector_type(4)));

// ---------------------------------------------------------------- reductions
__device__ inline float block_sum192(float v, float* sm) {
  #pragma unroll
  for (int o = 32; o > 0; o >>= 1) v += __shfl_down(v, o, 64);
  const int lane = threadIdx.x & 63, w = threadIdx.x >> 6;
  __syncthreads();                 // protect sm reuse across calls
  if (lane == 0) sm[w] = v;
  __syncthreads();
  return sm[0] + sm[1] + sm[2];
}

// ---------------- Kernel 1: ragged mean-pool + enrich + LayerNorm -> bf16 ---
__global__ __launch_bounds__(192) void k_pool_ln(
    const int* __restrict__ token_ids, const int* __restrict__ segment_ids,
    const int* __restrict__ section_ids, const int* __restrict__ temporality_ids,
    const int* __restrict__ negation_ids, const int* __restrict__ position_ids,
    const int* __restrict__ timestamp_ids,
    const float* __restrict__ token_table, const float* __restrict__ section_table,
    const float* __restrict__ temporality_table, const float* __restrict__ negation_table,
    const float* __restrict__ position_table, const float* __restrict__ timestamp_table,
    const float* __restrict__ gamma, const float* __restrict__ beta,
    bf16* __restrict__ out_normed)
{
  const int n = blockIdx.x;          // sentence slot 0..4095
  const int tid = threadIdx.x;       // 0..191, each owns 4 dims (float4)
  __shared__ float red[3];

  // binary search sorted segment_ids for [start, end) of segment n (uniform)
  int lo = 0, hi = Tn;
  while (lo < hi) { int mid = (lo + hi) >> 1; if (segment_ids[mid] < n) lo = mid + 1; else hi = mid; }
  const int start = lo;
  hi = Tn;
  while (lo < hi) { int mid = (lo + hi) >> 1; if (segment_ids[mid] < n + 1) lo = mid + 1; else hi = mid; }
  const int end = lo;
  const float scale = 1.0f / fmaxf((float)(end - start), 1.0f);

  float4 acc = make_float4(0.f, 0.f, 0.f, 0.f);
  for (int t = start; t < end; ++t) {
    const int tok = token_ids[t];
    const float4 v = *(const float4*)(token_table + (size_t)tok * Dn + 4 * tid);
    acc.x += v.x; acc.y += v.y; acc.z += v.z; acc.w += v.w;
  }

  const int sec = section_ids[n];
  const int tmp = temporality_ids[n];
  const int neg = negation_ids[n];
  const int pos = position_ids[n];
  const int ts  = timestamp_ids[n];
  const float4 v1 = *(const float4*)(section_table     + (size_t)sec * Dn + 4 * tid);
  const float4 v2 = *(const float4*)(temporality_table + (size_t)tmp * Dn + 4 * tid);
  const float4 v3 = *(const float4*)(negation_table    + (size_t)neg * Dn + 4 * tid);
  const float4 v4 = *(const float4*)(position_table    + (size_t)pos * Dn + 4 * tid);
  const float4 v5 = *(const float4*)(timestamp_table   + (size_t)ts  * Dn + 4 * tid);

  float4 e;
  e.x = acc.x * scale + v1.x + v2.x + v3.x + v4.x + v5.x;
  e.y = acc.y * scale + v1.y + v2.y + v3.y + v4.y + v5.y;
  e.z = acc.z * scale + v1.z + v2.z + v3.z + v4.z + v5.z;
  e.w = acc.w * scale + v1.w + v2.w + v3.w + v4.w + v5.w;

  // LayerNorm (two-pass for numerical safety)
  const float mu = block_sum192(e.x + e.y + e.z + e.w, red) * (1.0f / 768.0f);
  const float dx = e.x - mu, dy = e.y - mu, dz = e.z - mu, dw = e.w - mu;
  const float var = block_sum192(dx*dx + dy*dy + dz*dz + dw*dw, red) * (1.0f / 768.0f);
  const float inv = rsqrtf(var + 1e-5f);

  const float4 g = *(const float4*)(gamma + 4 * tid);
  const float4 b = *(const float4*)(beta  + 4 * tid);
  alignas(8) bf16 o[4];
  o[0] = (bf16)(dx * inv * g.x + b.x);
  o[1] = (bf16)(dy * inv * g.y + b.y);
  o[2] = (bf16)(dz * inv * g.z + b.z);
  o[3] = (bf16)(dw * inv * g.w + b.w);
  *(ushort4*)(out_normed + (size_t)n * Dn + 4 * tid) = *(ushort4*)o;
}

// ---------------------------------- Kernel 2: proj_w fp32 -> bf16 ----------
__global__ __launch_bounds__(256) void k_cvt_w(const float* __restrict__ w,
                                               bf16* __restrict__ wb) {
  const int i = blockIdx.x * 256 + threadIdx.x;   // 147456 threads, 4 elems each
  const float4 v = ((const float4*)w)[i];
  alignas(8) bf16 o[4] = {(bf16)v.x, (bf16)v.y, (bf16)v.z, (bf16)v.w};
  ((ushort4*)wb)[i] = *(ushort4*)o;
}

// ---------------------------------- Kernel 3: padding mask = 0 -------------
__global__ __launch_bounds__(256) void k_mask(float* __restrict__ out) {
  out[blockIdx.x * 256 + threadIdx.x] = 0.0f;     // 16 blocks x 256 = 4096
}

// ------------- Kernel 4: out = normed @ W^T + bias  (bf16 MFMA) -------------
// A: [4096,768] bf16 row-major.  W: [768,768] bf16 row-major ([e][d] = [N][K]).
// 128x128 tile, BK=32, 4 waves each computing a 64x64 subtile of 16x16 MFMAs.
__global__ __launch_bounds__(256) void k_gemm(
    const bf16* __restrict__ A, const bf16* __restrict__ W,
    const float* __restrict__ bias, float* __restrict__ out)
{
  __shared__ bf16 As[128 * 32];
  __shared__ bf16 Bs[128 * 32];
  const int tid  = threadIdx.x;
  const int lane = tid & 63;
  const int w    = tid >> 6;
  const int m0 = blockIdx.y * 128;
  const int n0 = blockIdx.x * 128;
  const int wm = (w >> 1) * 64;
  const int wn = (w & 1) * 64;

  f32x4 acc[4][4];
  #pragma unroll
  for (int i = 0; i < 4; ++i)
    #pragma unroll
    for (int j = 0; j < 4; ++j) acc[i][j] = (f32x4){0.f, 0.f, 0.f, 0.f};

  // staging coords: thread t covers tile row t>>2, cols ((t&3)*8..+7); chunk 2 = rows+64
  const int fr = tid >> 2;
  const int fc = (tid & 3) * 8;
  const bf16* agp = A + (size_t)(m0 + fr) * 768 + fc;
  const bf16* bgp = W + (size_t)(n0 + fr) * 768 + fc;

  for (int kt = 0; kt < 24; ++kt) {
    __syncthreads();   // previous iter's ds_reads done before overwrite
    #pragma unroll
    for (int it = 0; it < 2; ++it) {
      const int f = it * 256 + tid;
      __builtin_amdgcn_global_load_lds(
          (const __attribute__((address_space(1))) void*)(agp + (size_t)it * 64 * 768 + kt * 32),
          (__attribute__((address_space(3))) void*)(As + f * 8), 16, 0, 0);
      __builtin_amdgcn_global_load_lds(
          (const __attribute__((address_space(1))) void*)(bgp + (size_t)it * 64 * 768 + kt * 32),
          (__attribute__((address_space(3))) void*)(Bs + f * 8), 16, 0, 0);
    }
    __syncthreads();   // drain global_load_lds (vmcnt) + all waves see tiles

    bf16x8 af[4], bfr[4];
    #pragma unroll
    for (int i = 0; i < 4; ++i)
      af[i] = *(const bf16x8*)(As + (wm + i * 16 + (lane & 15)) * 32 + (lane >> 4) * 8);
    #pragma unroll
    for (int j = 0; j < 4; ++j)
      bfr[j] = *(const bf16x8*)(Bs + (wn + j * 16 + (lane & 15)) * 32 + (lane >> 4) * 8);

    #pragma unroll
    for (int i = 0; i < 4; ++i)
      #pragma unroll
      for (int j = 0; j < 4; ++j)
        acc[i][j] = __builtin_amdgcn_mfma_f32_16x16x32_bf16(af[i], bfr[j], acc[i][j], 0, 0, 0);
  }

  // epilogue: D mapping col=lane&15, row=(lane>>4)*4+reg
  float bvals[4];
  #pragma unroll
  for (int j = 0; j < 4; ++j) bvals[j] = bias[n0 + wn + j * 16 + (lane & 15)];
  const int r0 = (lane >> 4) * 4;
  #pragma unroll
  for (int i = 0; i < 4; ++i) {
    #pragma unroll
    for (int r = 0; r < 4; ++r) {
      const int gm = m0 + wm + i * 16 + r0 + r;
      float* orow = out + (size_t)gm * 768 + n0 + wn;
      #pragma unroll
      for (int j = 0; j < 4; ++j)
        orow[j * 16 + (lane & 15)] = acc[i][j][r] + bvals[j];
    }
  }
}

extern "C" void kernel_launch(void* const* d_in, const int* in_sizes, int n_in,
                              void* d_out, int out_size, void* d_ws, size_t ws_size,
                              hipStream_t stream) {
  const int* token_ids       = (const int*)d_in[0];
  const int* segment_ids     = (const int*)d_in[1];
  const int* section_ids     = (const int*)d_in[2];
  const int* temporality_ids = (const int*)d_in[3];
  const int* negation_ids    = (const int*)d_in[4];
  const int* position_ids    = (const int*)d_in[5];
  const int* timestamp_ids   = (const int*)d_in[6];
  const float* token_table       = (const float*)d_in[7];
  const float* section_table     = (const float*)d_in[8];
  const float* temporality_table = (const float*)d_in[9];
  const float* negation_table    = (const float*)d_in[10];
  const float* position_table    = (const float*)d_in[11];
  const float* timestamp_table   = (const float*)d_in[12];
  const float* ln_gamma = (const float*)d_in[13];
  const float* ln_beta  = (const float*)d_in[14];
  const float* proj_w   = (const float*)d_in[15];
  const float* proj_b   = (const float*)d_in[16];

  float* out = (float*)d_out;
  bf16* wsW = (bf16*)d_ws;                       // 768*768 bf16   (1.18 MB)
  bf16* wsN = (bf16*)d_ws + (size_t)Dn * Dn;     // 4096*768 bf16  (6.29 MB)

  // W -> bf16 (589824 elems / 4 per thread = 147456 threads)
  k_cvt_w<<<576, 256, 0, stream>>>(proj_w, wsW);
  // pool + enrich + LN -> bf16 normed
  k_pool_ln<<<NSEG, 192, 0, stream>>>(token_ids, segment_ids, section_ids,
      temporality_ids, negation_ids, position_ids, timestamp_ids,
      token_table, section_table, temporality_table, negation_table,
      position_table, timestamp_table, ln_gamma, ln_beta, wsN);
  // padding mask (all False) = zeros at tail of d_out
  k_mask<<<16, 256, 0, stream>>>(out + (size_t)NSEG * Dn);
  // projection GEMM + bias
  k_gemm<<<dim3(6, 32), 256, 0, stream>>>(wsN, wsW, proj_b, out);
}

// Round 2
// 209.336 us; speedup vs baseline: 1.0464x; 1.0464x over previous
//
#include <hip/hip_runtime.h>
#include <stdint.h>

#define Tn 65536
#define Dn 768
#define NSEG 4096   // B*S = 32*128

typedef __bf16 bf16;
typedef __bf16 bf16x8 __attribute__((ext_vector_type(8)));
typedef float f32x4 __attribute__((ext_vector_type(4)));

__device__ inline void f4add(float4& a, const float4& v) {
  a.x += v.x; a.y += v.y; a.z += v.z; a.w += v.w;
}

// ---------------------------------------------------------------- reductions
__device__ inline float block_sum192(float v, float* sm) {
  #pragma unroll
  for (int o = 32; o > 0; o >>= 1) v += __shfl_down(v, o, 64);
  const int lane = threadIdx.x & 63, w = threadIdx.x >> 6;
  __syncthreads();                 // protect sm reuse across calls
  if (lane == 0) sm[w] = v;
  __syncthreads();
  return sm[0] + sm[1] + sm[2];
}

// ---------------- Kernel 1: ragged mean-pool + enrich + LayerNorm -> bf16 ---
__global__ __launch_bounds__(192) void k_pool_ln(
    const int* __restrict__ token_ids, const int* __restrict__ segment_ids,
    const int* __restrict__ section_ids, const int* __restrict__ temporality_ids,
    const int* __restrict__ negation_ids, const int* __restrict__ position_ids,
    const int* __restrict__ timestamp_ids,
    const float* __restrict__ token_table, const float* __restrict__ section_table,
    const float* __restrict__ temporality_table, const float* __restrict__ negation_table,
    const float* __restrict__ position_table, const float* __restrict__ timestamp_table,
    const float* __restrict__ gamma, const float* __restrict__ beta,
    bf16* __restrict__ out_normed)
{
  const int n = blockIdx.x;          // sentence slot 0..4095
  const int tid = threadIdx.x;       // 0..191, each owns 4 dims (float4)
  __shared__ float red[3];

  // binary search sorted segment_ids for [start, end) of segment n (uniform)
  int lo = 0, hi = Tn;
  while (lo < hi) { int mid = (lo + hi) >> 1; if (segment_ids[mid] < n) lo = mid + 1; else hi = mid; }
  const int start = lo;
  hi = Tn;
  while (lo < hi) { int mid = (lo + hi) >> 1; if (segment_ids[mid] < n + 1) lo = mid + 1; else hi = mid; }
  const int end = lo;
  const float scale = 1.0f / fmaxf((float)(end - start), 1.0f);

  // enrichment loads issued early to overlap with the gather loop
  const int sec = section_ids[n];
  const int tmp = temporality_ids[n];
  const int neg = negation_ids[n];
  const int pos = position_ids[n];
  const int ts  = timestamp_ids[n];
  const float4 v1 = *(const float4*)(section_table     + (size_t)sec * Dn + 4 * tid);
  const float4 v2 = *(const float4*)(temporality_table + (size_t)tmp * Dn + 4 * tid);
  const float4 v3 = *(const float4*)(negation_table    + (size_t)neg * Dn + 4 * tid);
  const float4 v4 = *(const float4*)(position_table    + (size_t)pos * Dn + 4 * tid);
  const float4 v5 = *(const float4*)(timestamp_table   + (size_t)ts  * Dn + 4 * tid);

  // ragged gather-mean, unrolled x4 with independent accumulators (MLP)
  const float4* tt = (const float4*)token_table;   // row stride = 192 float4
  float4 a0 = make_float4(0.f,0.f,0.f,0.f), a1 = a0, a2 = a0, a3 = a0;
  int t = start;
  for (; t + 4 <= end; t += 4) {
    const int i0 = token_ids[t + 0];
    const int i1 = token_ids[t + 1];
    const int i2 = token_ids[t + 2];
    const int i3 = token_ids[t + 3];
    const float4 w0 = tt[(size_t)i0 * 192 + tid];
    const float4 w1 = tt[(size_t)i1 * 192 + tid];
    const float4 w2 = tt[(size_t)i2 * 192 + tid];
    const float4 w3 = tt[(size_t)i3 * 192 + tid];
    f4add(a0, w0); f4add(a1, w1); f4add(a2, w2); f4add(a3, w3);
  }
  for (; t < end; ++t) {
    const float4 w0 = tt[(size_t)token_ids[t] * 192 + tid];
    f4add(a0, w0);
  }
  f4add(a0, a1); f4add(a2, a3); f4add(a0, a2);

  float4 e;
  e.x = a0.x * scale + v1.x + v2.x + v3.x + v4.x + v5.x;
  e.y = a0.y * scale + v1.y + v2.y + v3.y + v4.y + v5.y;
  e.z = a0.z * scale + v1.z + v2.z + v3.z + v4.z + v5.z;
  e.w = a0.w * scale + v1.w + v2.w + v3.w + v4.w + v5.w;

  // LayerNorm (two-pass)
  const float mu = block_sum192(e.x + e.y + e.z + e.w, red) * (1.0f / 768.0f);
  const float dx = e.x - mu, dy = e.y - mu, dz = e.z - mu, dw = e.w - mu;
  const float var = block_sum192(dx*dx + dy*dy + dz*dz + dw*dw, red) * (1.0f / 768.0f);
  const float inv = rsqrtf(var + 1e-5f);

  const float4 g = *(const float4*)(gamma + 4 * tid);
  const float4 b = *(const float4*)(beta  + 4 * tid);
  alignas(8) bf16 o[4];
  o[0] = (bf16)(dx * inv * g.x + b.x);
  o[1] = (bf16)(dy * inv * g.y + b.y);
  o[2] = (bf16)(dz * inv * g.z + b.z);
  o[3] = (bf16)(dw * inv * g.w + b.w);
  *(ushort4*)(out_normed + (size_t)n * Dn + 4 * tid) = *(ushort4*)o;
}

// ------------- Kernel 2: proj_w fp32 -> bf16, + zero the padding mask -------
__global__ __launch_bounds__(256) void k_cvt_mask(const float* __restrict__ w,
                                                  bf16* __restrict__ wb,
                                                  float* __restrict__ mask_out) {
  const int b = blockIdx.x;
  if (b < 576) {
    const int i = b * 256 + threadIdx.x;   // 147456 threads, 4 elems each
    const float4 v = ((const float4*)w)[i];
    alignas(8) bf16 o[4] = {(bf16)v.x, (bf16)v.y, (bf16)v.z, (bf16)v.w};
    ((ushort4*)wb)[i] = *(ushort4*)o;
  } else {
    mask_out[(b - 576) * 256 + threadIdx.x] = 0.0f;   // 16 blocks x 256 = 4096
  }
}

// ------------- Kernel 3: out = normed @ W^T + bias  (bf16 MFMA) -------------
// A: [4096,768] bf16 row-major.  W: [768,768] bf16 row-major ([e][d] = [N][K]).
// BM=64, BN=128, BK=32 -> grid 6x64 = 384 blocks (vs 192 before).
// 4 waves, each computing a 32x64 subtile (acc[2][4] of 16x16 MFMAs).
__global__ __launch_bounds__(256) void k_gemm(
    const bf16* __restrict__ A, const bf16* __restrict__ W,
    const float* __restrict__ bias, float* __restrict__ out)
{
  __shared__ bf16 As[64 * 32];    // 4 KB
  __shared__ bf16 Bs[128 * 32];   // 8 KB
  const int tid  = threadIdx.x;
  const int lane = tid & 63;
  const int w    = tid >> 6;
  const int m0 = blockIdx.y * 64;
  const int n0 = blockIdx.x * 128;
  const int wm = (w >> 1) * 32;
  const int wn = (w & 1) * 64;

  f32x4 acc[2][4];
  #pragma unroll
  for (int i = 0; i < 2; ++i)
    #pragma unroll
    for (int j = 0; j < 4; ++j) acc[i][j] = (f32x4){0.f, 0.f, 0.f, 0.f};

  // staging coords: thread t covers tile row t>>2, cols ((t&3)*8..+7)
  const int fr = tid >> 2;
  const int fc = (tid & 3) * 8;
  const bf16* agp = A + (size_t)(m0 + fr) * 768 + fc;
  const bf16* bgp = W + (size_t)(n0 + fr) * 768 + fc;

  for (int kt = 0; kt < 24; ++kt) {
    __syncthreads();   // previous iter's ds_reads done before overwrite
    __builtin_amdgcn_global_load_lds(
        (const __attribute__((address_space(1))) void*)(agp + kt * 32),
        (__attribute__((address_space(3))) void*)(As + tid * 8), 16, 0, 0);
    #pragma unroll
    for (int it = 0; it < 2; ++it) {
      const int f = it * 256 + tid;
      __builtin_amdgcn_global_load_lds(
          (const __attribute__((address_space(1))) void*)(bgp + (size_t)it * 64 * 768 + kt * 32),
          (__attribute__((address_space(3))) void*)(Bs + f * 8), 16, 0, 0);
    }
    __syncthreads();   // drain global_load_lds + all waves see tiles

    bf16x8 af[2], bfr[4];
    #pragma unroll
    for (int i = 0; i < 2; ++i)
      af[i] = *(const bf16x8*)(As + (wm + i * 16 + (lane & 15)) * 32 + (lane >> 4) * 8);
    #pragma unroll
    for (int j = 0; j < 4; ++j)
      bfr[j] = *(const bf16x8*)(Bs + (wn + j * 16 + (lane & 15)) * 32 + (lane >> 4) * 8);

    #pragma unroll
    for (int i = 0; i < 2; ++i)
      #pragma unroll
      for (int j = 0; j < 4; ++j)
        acc[i][j] = __builtin_amdgcn_mfma_f32_16x16x32_bf16(af[i], bfr[j], acc[i][j], 0, 0, 0);
  }

  // epilogue: D mapping col=lane&15, row=(lane>>4)*4+reg
  float bvals[4];
  #pragma unroll
  for (int j = 0; j < 4; ++j) bvals[j] = bias[n0 + wn + j * 16 + (lane & 15)];
  const int r0 = (lane >> 4) * 4;
  #pragma unroll
  for (int i = 0; i < 2; ++i) {
    #pragma unroll
    for (int r = 0; r < 4; ++r) {
      const int gm = m0 + wm + i * 16 + r0 + r;
      float* orow = out + (size_t)gm * 768 + n0 + wn;
      #pragma unroll
      for (int j = 0; j < 4; ++j)
        orow[j * 16 + (lane & 15)] = acc[i][j][r] + bvals[j];
    }
  }
}

extern "C" void kernel_launch(void* const* d_in, const int* in_sizes, int n_in,
                              void* d_out, int out_size, void* d_ws, size_t ws_size,
                              hipStream_t stream) {
  const int* token_ids       = (const int*)d_in[0];
  const int* segment_ids     = (const int*)d_in[1];
  const int* section_ids     = (const int*)d_in[2];
  const int* temporality_ids = (const int*)d_in[3];
  const int* negation_ids    = (const int*)d_in[4];
  const int* position_ids    = (const int*)d_in[5];
  const int* timestamp_ids   = (const int*)d_in[6];
  const float* token_table       = (const float*)d_in[7];
  const float* section_table     = (const float*)d_in[8];
  const float* temporality_table = (const float*)d_in[9];
  const float* negation_table    = (const float*)d_in[10];
  const float* position_table    = (const float*)d_in[11];
  const float* timestamp_table   = (const float*)d_in[12];
  const float* ln_gamma = (const float*)d_in[13];
  const float* ln_beta  = (const float*)d_in[14];
  const float* proj_w   = (const float*)d_in[15];
  const float* proj_b   = (const float*)d_in[16];

  float* out = (float*)d_out;
  bf16* wsW = (bf16*)d_ws;                       // 768*768 bf16   (1.18 MB)
  bf16* wsN = (bf16*)d_ws + (size_t)Dn * Dn;     // 4096*768 bf16  (6.29 MB)

  // W -> bf16 (576 blocks) + padding-mask zeros (16 blocks)
  k_cvt_mask<<<592, 256, 0, stream>>>(proj_w, wsW, out + (size_t)NSEG * Dn);
  // pool + enrich + LN -> bf16 normed
  k_pool_ln<<<NSEG, 192, 0, stream>>>(token_ids, segment_ids, section_ids,
      temporality_ids, negation_ids, position_ids, timestamp_ids,
      token_table, section_table, temporality_table, negation_table,
      position_table, timestamp_table, ln_gamma, ln_beta, wsN);
  // projection GEMM + bias
  k_gemm<<<dim3(6, 64), 256, 0, stream>>>(wsN, wsW, proj_b, out);
}

// Round 3
// 203.277 us; speedup vs baseline: 1.0776x; 1.0298x over previous
//
#include <hip/hip_runtime.h>
#include <stdint.h>

#define Tn 65536
#define Dn 768
#define NSEG 4096   // B*S = 32*128

typedef __bf16 bf16;
typedef __bf16 bf16x8 __attribute__((ext_vector_type(8)));
typedef float f32x4 __attribute__((ext_vector_type(4)));

__device__ inline void f4add(float4& a, const float4& v) {
  a.x += v.x; a.y += v.y; a.z += v.z; a.w += v.w;
}

// ---- Kernel 1: proj_w fp32->bf16  +  padding-mask zeros  +  segment bounds -
// blocks [0,576): convert W; [576,592): zero mask; [592,848): segment starts.
__global__ __launch_bounds__(256) void k_prep(
    const float* __restrict__ w, bf16* __restrict__ wb,
    float* __restrict__ mask_out,
    const int* __restrict__ seg, int* __restrict__ starts)
{
  const int b = blockIdx.x;
  if (b < 576) {
    const int i = b * 256 + threadIdx.x;   // 147456 threads, 4 elems each
    const float4 v = ((const float4*)w)[i];
    alignas(8) bf16 o[4] = {(bf16)v.x, (bf16)v.y, (bf16)v.z, (bf16)v.w};
    ((ushort4*)wb)[i] = *(ushort4*)o;
  } else if (b < 592) {
    mask_out[(b - 576) * 256 + threadIdx.x] = 0.0f;   // 16x256 = 4096
  } else {
    const int t = (b - 592) * 256 + threadIdx.x;      // 0..65535
    const int s = seg[t];
    const int sp = (t == 0) ? -1 : seg[t - 1];
    for (int k = sp + 1; k <= s; ++k) starts[k] = t;  // first idx with seg>=k
    if (t == Tn - 1)
      for (int k = s + 1; k <= NSEG; ++k) starts[k] = Tn;
  }
}

// ---------------- Kernel 2: ragged mean-pool + enrich + LayerNorm -> bf16 ---
// One wave per sentence slot; lane owns 3 float4 (12 dims). No __syncthreads.
__global__ __launch_bounds__(64) void k_pool_ln(
    const int* __restrict__ token_ids, const int* __restrict__ starts,
    const int* __restrict__ section_ids, const int* __restrict__ temporality_ids,
    const int* __restrict__ negation_ids, const int* __restrict__ position_ids,
    const int* __restrict__ timestamp_ids,
    const float* __restrict__ token_table, const float* __restrict__ section_table,
    const float* __restrict__ temporality_table, const float* __restrict__ negation_table,
    const float* __restrict__ position_table, const float* __restrict__ timestamp_table,
    const float* __restrict__ gamma, const float* __restrict__ beta,
    bf16* __restrict__ out_normed)
{
  const int n = blockIdx.x;
  const int lane = threadIdx.x;
  const int start = starts[n];
  const int end   = starts[n + 1];
  const float scale = 1.0f / fmaxf((float)(end - start), 1.0f);

  const float4* tt = (const float4*)token_table;   // row stride = 192 float4

  // enrichment rows (issued early; ids are wave-uniform scalar loads)
  const float4* e1 = (const float4*)(section_table     + (size_t)section_ids[n]     * Dn);
  const float4* e2 = (const float4*)(temporality_table + (size_t)temporality_ids[n] * Dn);
  const float4* e3 = (const float4*)(negation_table    + (size_t)negation_ids[n]    * Dn);
  const float4* e4 = (const float4*)(position_table    + (size_t)position_ids[n]    * Dn);
  const float4* e5 = (const float4*)(timestamp_table   + (size_t)timestamp_ids[n]   * Dn);
  float4 en[3];
  #pragma unroll
  for (int j = 0; j < 3; ++j) {
    const int d = j * 64 + lane;
    float4 q = e1[d];
    f4add(q, e2[d]); f4add(q, e3[d]); f4add(q, e4[d]); f4add(q, e5[d]);
    en[j] = q;
  }

  // ragged gather-mean, 4-token batches => 12 outstanding 16B loads/lane
  float4 acc[3];
  #pragma unroll
  for (int j = 0; j < 3; ++j) acc[j] = make_float4(0.f, 0.f, 0.f, 0.f);
  int t = start;
  for (; t + 4 <= end; t += 4) {
    const int i0 = token_ids[t + 0];
    const int i1 = token_ids[t + 1];
    const int i2 = token_ids[t + 2];
    const int i3 = token_ids[t + 3];
    const float4* r0 = tt + (size_t)i0 * 192;
    const float4* r1 = tt + (size_t)i1 * 192;
    const float4* r2 = tt + (size_t)i2 * 192;
    const float4* r3 = tt + (size_t)i3 * 192;
    float4 L[4][3];
    #pragma unroll
    for (int j = 0; j < 3; ++j) {
      const int d = j * 64 + lane;
      L[0][j] = r0[d]; L[1][j] = r1[d]; L[2][j] = r2[d]; L[3][j] = r3[d];
    }
    #pragma unroll
    for (int j = 0; j < 3; ++j) {
      f4add(L[0][j], L[1][j]); f4add(L[2][j], L[3][j]);
      f4add(L[0][j], L[2][j]); f4add(acc[j], L[0][j]);
    }
  }
  for (; t < end; ++t) {
    const float4* r = tt + (size_t)token_ids[t] * 192;
    #pragma unroll
    for (int j = 0; j < 3; ++j) f4add(acc[j], r[j * 64 + lane]);
  }

  float4 e[3];
  #pragma unroll
  for (int j = 0; j < 3; ++j) {
    e[j].x = acc[j].x * scale + en[j].x;
    e[j].y = acc[j].y * scale + en[j].y;
    e[j].z = acc[j].z * scale + en[j].z;
    e[j].w = acc[j].w * scale + en[j].w;
  }

  // LayerNorm via wave butterfly (all lanes end with the total)
  float s = 0.f;
  #pragma unroll
  for (int j = 0; j < 3; ++j) s += e[j].x + e[j].y + e[j].z + e[j].w;
  #pragma unroll
  for (int o = 32; o > 0; o >>= 1) s += __shfl_xor(s, o, 64);
  const float mu = s * (1.0f / 768.0f);

  float v = 0.f;
  #pragma unroll
  for (int j = 0; j < 3; ++j) {
    e[j].x -= mu; e[j].y -= mu; e[j].z -= mu; e[j].w -= mu;
    v += e[j].x * e[j].x + e[j].y * e[j].y + e[j].z * e[j].z + e[j].w * e[j].w;
  }
  #pragma unroll
  for (int o = 32; o > 0; o >>= 1) v += __shfl_xor(v, o, 64);
  const float inv = rsqrtf(v * (1.0f / 768.0f) + 1e-5f);

  #pragma unroll
  for (int j = 0; j < 3; ++j) {
    const int d = j * 64 + lane;
    const float4 g = ((const float4*)gamma)[d];
    const float4 b = ((const float4*)beta)[d];
    alignas(8) bf16 o[4];
    o[0] = (bf16)(e[j].x * inv * g.x + b.x);
    o[1] = (bf16)(e[j].y * inv * g.y + b.y);
    o[2] = (bf16)(e[j].z * inv * g.z + b.z);
    o[3] = (bf16)(e[j].w * inv * g.w + b.w);
    *(ushort4*)(out_normed + (size_t)n * Dn + 4 * d) = *(ushort4*)o;
  }
}

// ------------- Kernel 3: out = normed @ W^T + bias  (bf16 MFMA) -------------
// A: [4096,768] bf16 row-major.  W: [768,768] bf16 row-major ([e][d] = [N][K]).
// BM=64, BN=128, BK=32 -> grid 6x64 = 384 blocks.
__global__ __launch_bounds__(256) void k_gemm(
    const bf16* __restrict__ A, const bf16* __restrict__ W,
    const float* __restrict__ bias, float* __restrict__ out)
{
  __shared__ bf16 As[64 * 32];    // 4 KB
  __shared__ bf16 Bs[128 * 32];   // 8 KB
  const int tid  = threadIdx.x;
  const int lane = tid & 63;
  const int w    = tid >> 6;
  const int m0 = blockIdx.y * 64;
  const int n0 = blockIdx.x * 128;
  const int wm = (w >> 1) * 32;
  const int wn = (w & 1) * 64;

  f32x4 acc[2][4];
  #pragma unroll
  for (int i = 0; i < 2; ++i)
    #pragma unroll
    for (int j = 0; j < 4; ++j) acc[i][j] = (f32x4){0.f, 0.f, 0.f, 0.f};

  const int fr = tid >> 2;
  const int fc = (tid & 3) * 8;
  const bf16* agp = A + (size_t)(m0 + fr) * 768 + fc;
  const bf16* bgp = W + (size_t)(n0 + fr) * 768 + fc;

  for (int kt = 0; kt < 24; ++kt) {
    __syncthreads();
    __builtin_amdgcn_global_load_lds(
        (const __attribute__((address_space(1))) void*)(agp + kt * 32),
        (__attribute__((address_space(3))) void*)(As + tid * 8), 16, 0, 0);
    #pragma unroll
    for (int it = 0; it < 2; ++it) {
      const int f = it * 256 + tid;
      __builtin_amdgcn_global_load_lds(
          (const __attribute__((address_space(1))) void*)(bgp + (size_t)it * 64 * 768 + kt * 32),
          (__attribute__((address_space(3))) void*)(Bs + f * 8), 16, 0, 0);
    }
    __syncthreads();

    bf16x8 af[2], bfr[4];
    #pragma unroll
    for (int i = 0; i < 2; ++i)
      af[i] = *(const bf16x8*)(As + (wm + i * 16 + (lane & 15)) * 32 + (lane >> 4) * 8);
    #pragma unroll
    for (int j = 0; j < 4; ++j)
      bfr[j] = *(const bf16x8*)(Bs + (wn + j * 16 + (lane & 15)) * 32 + (lane >> 4) * 8);

    #pragma unroll
    for (int i = 0; i < 2; ++i)
      #pragma unroll
      for (int j = 0; j < 4; ++j)
        acc[i][j] = __builtin_amdgcn_mfma_f32_16x16x32_bf16(af[i], bfr[j], acc[i][j], 0, 0, 0);
  }

  float bvals[4];
  #pragma unroll
  for (int j = 0; j < 4; ++j) bvals[j] = bias[n0 + wn + j * 16 + (lane & 15)];
  const int r0 = (lane >> 4) * 4;
  #pragma unroll
  for (int i = 0; i < 2; ++i) {
    #pragma unroll
    for (int r = 0; r < 4; ++r) {
      const int gm = m0 + wm + i * 16 + r0 + r;
      float* orow = out + (size_t)gm * 768 + n0 + wn;
      #pragma unroll
      for (int j = 0; j < 4; ++j)
        orow[j * 16 + (lane & 15)] = acc[i][j][r] + bvals[j];
    }
  }
}

extern "C" void kernel_launch(void* const* d_in, const int* in_sizes, int n_in,
                              void* d_out, int out_size, void* d_ws, size_t ws_size,
                              hipStream_t stream) {
  const int* token_ids       = (const int*)d_in[0];
  const int* segment_ids     = (const int*)d_in[1];
  const int* section_ids     = (const int*)d_in[2];
  const int* temporality_ids = (const int*)d_in[3];
  const int* negation_ids    = (const int*)d_in[4];
  const int* position_ids    = (const int*)d_in[5];
  const int* timestamp_ids   = (const int*)d_in[6];
  const float* token_table       = (const float*)d_in[7];
  const float* section_table     = (const float*)d_in[8];
  const float* temporality_table = (const float*)d_in[9];
  const float* negation_table    = (const float*)d_in[10];
  const float* position_table    = (const float*)d_in[11];
  const float* timestamp_table   = (const float*)d_in[12];
  const float* ln_gamma = (const float*)d_in[13];
  const float* ln_beta  = (const float*)d_in[14];
  const float* proj_w   = (const float*)d_in[15];
  const float* proj_b   = (const float*)d_in[16];

  float* out = (float*)d_out;
  bf16* wsW = (bf16*)d_ws;                        // 768*768 bf16   (1.18 MB)
  bf16* wsN = wsW + (size_t)Dn * Dn;              // 4096*768 bf16  (6.29 MB)
  int*  wsS = (int*)((char*)d_ws + (size_t)(Dn * Dn + NSEG * Dn) * 2);  // 4097 ints

  // W->bf16 (576) + mask zeros (16) + segment bounds (256)
  k_prep<<<848, 256, 0, stream>>>(proj_w, wsW, out + (size_t)NSEG * Dn,
                                  segment_ids, wsS);
  // pool + enrich + LN -> bf16 normed (one wave per segment)
  k_pool_ln<<<NSEG, 64, 0, stream>>>(token_ids, wsS, section_ids,
      temporality_ids, negation_ids, position_ids, timestamp_ids,
      token_table, section_table, temporality_table, negation_table,
      position_table, timestamp_table, ln_gamma, ln_beta, wsN);
  // projection GEMM + bias
  k_gemm<<<dim3(6, 64), 256, 0, stream>>>(wsN, wsW, proj_b, out);
}

// Round 4
// 202.782 us; speedup vs baseline: 1.0802x; 1.0024x over previous
//
#include <hip/hip_runtime.h>
#include <stdint.h>

#define Tn 65536
#define Dn 768
#define NSEG 4096   // B*S = 32*128

typedef __bf16 bf16;
typedef __bf16 bf16x8 __attribute__((ext_vector_type(8)));
typedef float f32x4 __attribute__((ext_vector_type(4)));

__device__ inline void f4add(float4& a, const float4& v) {
  a.x += v.x; a.y += v.y; a.z += v.z; a.w += v.w;
}

// ---- Kernel 1: proj_w fp32->bf16  +  padding-mask zeros  +  segment bounds -
// blocks [0,576): convert W; [576,592): zero mask; [592,848): segment starts.
__global__ __launch_bounds__(256) void k_prep(
    const float* __restrict__ w, bf16* __restrict__ wb,
    float* __restrict__ mask_out,
    const int* __restrict__ seg, int* __restrict__ starts)
{
  const int b = blockIdx.x;
  if (b < 576) {
    const int i = b * 256 + threadIdx.x;   // 147456 threads, 4 elems each
    const float4 v = ((const float4*)w)[i];
    alignas(8) bf16 o[4] = {(bf16)v.x, (bf16)v.y, (bf16)v.z, (bf16)v.w};
    ((ushort4*)wb)[i] = *(ushort4*)o;
  } else if (b < 592) {
    mask_out[(b - 576) * 256 + threadIdx.x] = 0.0f;   // 16x256 = 4096
  } else {
    const int t = (b - 592) * 256 + threadIdx.x;      // 0..65535
    const int s = seg[t];
    const int sp = (t == 0) ? -1 : seg[t - 1];
    for (int k = sp + 1; k <= s; ++k) starts[k] = t;  // first idx with seg>=k
    if (t == Tn - 1)
      for (int k = s + 1; k <= NSEG; ++k) starts[k] = Tn;
  }
}

// ---------------- Kernel 2: ragged mean-pool + enrich + LayerNorm -> bf16 ---
// One wave per sentence slot; lane owns 3 float4 (12 dims). No __syncthreads.
// 8-token batches: 24 outstanding 16B loads/lane; next batch's ids prefetched
// (wave-uniform -> SGPRs) before the accumulate tree consumes the loads.
__global__ void k_pool_ln(
    const int* __restrict__ token_ids, const int* __restrict__ starts,
    const int* __restrict__ section_ids, const int* __restrict__ temporality_ids,
    const int* __restrict__ negation_ids, const int* __restrict__ position_ids,
    const int* __restrict__ timestamp_ids,
    const float* __restrict__ token_table, const float* __restrict__ section_table,
    const float* __restrict__ temporality_table, const float* __restrict__ negation_table,
    const float* __restrict__ position_table, const float* __restrict__ timestamp_table,
    const float* __restrict__ gamma, const float* __restrict__ beta,
    bf16* __restrict__ out_normed)
{
  const int n = blockIdx.x;
  const int lane = threadIdx.x;
  const int start = starts[n];
  const int end   = starts[n + 1];
  const float scale = 1.0f / fmaxf((float)(end - start), 1.0f);

  const float4* tt = (const float4*)token_table;   // row stride = 192 float4

  // enrichment rows (issued early; ids are wave-uniform scalar loads)
  const float4* e1 = (const float4*)(section_table     + (size_t)section_ids[n]     * Dn);
  const float4* e2 = (const float4*)(temporality_table + (size_t)temporality_ids[n] * Dn);
  const float4* e3 = (const float4*)(negation_table    + (size_t)negation_ids[n]    * Dn);
  const float4* e4 = (const float4*)(position_table    + (size_t)position_ids[n]    * Dn);
  const float4* e5 = (const float4*)(timestamp_table   + (size_t)timestamp_ids[n]   * Dn);
  float4 en[3];
  #pragma unroll
  for (int j = 0; j < 3; ++j) {
    const int d = j * 64 + lane;
    float4 q = e1[d];
    f4add(q, e2[d]); f4add(q, e3[d]); f4add(q, e4[d]); f4add(q, e5[d]);
    en[j] = q;
  }

  float4 acc[3];
  #pragma unroll
  for (int j = 0; j < 3; ++j) acc[j] = make_float4(0.f, 0.f, 0.f, 0.f);

  // ids for the first batch (clamped so prefetch never reads OOB)
  int t = start;
  int ids[8];
  #pragma unroll
  for (int u = 0; u < 8; ++u)
    ids[u] = token_ids[(t + u < Tn) ? t + u : Tn - 1];

  while (t + 8 <= end) {
    float4 L[8][3];
    #pragma unroll
    for (int u = 0; u < 8; ++u) {
      const float4* r = tt + (size_t)ids[u] * 192;
      #pragma unroll
      for (int j = 0; j < 3; ++j) L[u][j] = r[j * 64 + lane];
    }
    t += 8;
    // prefetch next batch's ids while the 24 loads are in flight
    #pragma unroll
    for (int u = 0; u < 8; ++u)
      ids[u] = token_ids[(t + u < Tn) ? t + u : Tn - 1];
    #pragma unroll
    for (int j = 0; j < 3; ++j) {
      f4add(L[0][j], L[1][j]); f4add(L[2][j], L[3][j]);
      f4add(L[4][j], L[5][j]); f4add(L[6][j], L[7][j]);
      f4add(L[0][j], L[2][j]); f4add(L[4][j], L[6][j]);
      f4add(L[0][j], L[4][j]); f4add(acc[j], L[0][j]);
    }
  }
  // tail (<8 tokens): ids[] already holds ids for t..t+7
  for (int u = 0; t < end; ++t, ++u) {
    const float4* r = tt + (size_t)ids[u] * 192;
    #pragma unroll
    for (int j = 0; j < 3; ++j) f4add(acc[j], r[j * 64 + lane]);
  }

  float4 e[3];
  #pragma unroll
  for (int j = 0; j < 3; ++j) {
    e[j].x = acc[j].x * scale + en[j].x;
    e[j].y = acc[j].y * scale + en[j].y;
    e[j].z = acc[j].z * scale + en[j].z;
    e[j].w = acc[j].w * scale + en[j].w;
  }

  // LayerNorm via wave butterfly (all lanes end with the total)
  float s = 0.f;
  #pragma unroll
  for (int j = 0; j < 3; ++j) s += e[j].x + e[j].y + e[j].z + e[j].w;
  #pragma unroll
  for (int o = 32; o > 0; o >>= 1) s += __shfl_xor(s, o, 64);
  const float mu = s * (1.0f / 768.0f);

  float v = 0.f;
  #pragma unroll
  for (int j = 0; j < 3; ++j) {
    e[j].x -= mu; e[j].y -= mu; e[j].z -= mu; e[j].w -= mu;
    v += e[j].x * e[j].x + e[j].y * e[j].y + e[j].z * e[j].z + e[j].w * e[j].w;
  }
  #pragma unroll
  for (int o = 32; o > 0; o >>= 1) v += __shfl_xor(v, o, 64);
  const float inv = rsqrtf(v * (1.0f / 768.0f) + 1e-5f);

  #pragma unroll
  for (int j = 0; j < 3; ++j) {
    const int d = j * 64 + lane;
    const float4 g = ((const float4*)gamma)[d];
    const float4 b = ((const float4*)beta)[d];
    alignas(8) bf16 o[4];
    o[0] = (bf16)(e[j].x * inv * g.x + b.x);
    o[1] = (bf16)(e[j].y * inv * g.y + b.y);
    o[2] = (bf16)(e[j].z * inv * g.z + b.z);
    o[3] = (bf16)(e[j].w * inv * g.w + b.w);
    *(ushort4*)(out_normed + (size_t)n * Dn + 4 * d) = *(ushort4*)o;
  }
}

// ------------- Kernel 3: out = normed @ W^T + bias  (bf16 MFMA) -------------
// A: [4096,768] bf16 row-major.  W: [768,768] bf16 row-major ([e][d] = [N][K]).
// BM=64, BN=128, BK=32 -> grid 6x64 = 384 blocks.
__global__ __launch_bounds__(256) void k_gemm(
    const bf16* __restrict__ A, const bf16* __restrict__ W,
    const float* __restrict__ bias, float* __restrict__ out)
{
  __shared__ bf16 As[64 * 32];    // 4 KB
  __shared__ bf16 Bs[128 * 32];   // 8 KB
  const int tid  = threadIdx.x;
  const int lane = tid & 63;
  const int w    = tid >> 6;
  const int m0 = blockIdx.y * 64;
  const int n0 = blockIdx.x * 128;
  const int wm = (w >> 1) * 32;
  const int wn = (w & 1) * 64;

  f32x4 acc[2][4];
  #pragma unroll
  for (int i = 0; i < 2; ++i)
    #pragma unroll
    for (int j = 0; j < 4; ++j) acc[i][j] = (f32x4){0.f, 0.f, 0.f, 0.f};

  const int fr = tid >> 2;
  const int fc = (tid & 3) * 8;
  const bf16* agp = A + (size_t)(m0 + fr) * 768 + fc;
  const bf16* bgp = W + (size_t)(n0 + fr) * 768 + fc;

  for (int kt = 0; kt < 24; ++kt) {
    __syncthreads();
    __builtin_amdgcn_global_load_lds(
        (const __attribute__((address_space(1))) void*)(agp + kt * 32),
        (__attribute__((address_space(3))) void*)(As + tid * 8), 16, 0, 0);
    #pragma unroll
    for (int it = 0; it < 2; ++it) {
      const int f = it * 256 + tid;
      __builtin_amdgcn_global_load_lds(
          (const __attribute__((address_space(1))) void*)(bgp + (size_t)it * 64 * 768 + kt * 32),
          (__attribute__((address_space(3))) void*)(Bs + f * 8), 16, 0, 0);
    }
    __syncthreads();

    bf16x8 af[2], bfr[4];
    #pragma unroll
    for (int i = 0; i < 2; ++i)
      af[i] = *(const bf16x8*)(As + (wm + i * 16 + (lane & 15)) * 32 + (lane >> 4) * 8);
    #pragma unroll
    for (int j = 0; j < 4; ++j)
      bfr[j] = *(const bf16x8*)(Bs + (wn + j * 16 + (lane & 15)) * 32 + (lane >> 4) * 8);

    #pragma unroll
    for (int i = 0; i < 2; ++i)
      #pragma unroll
      for (int j = 0; j < 4; ++j)
        acc[i][j] = __builtin_amdgcn_mfma_f32_16x16x32_bf16(af[i], bfr[j], acc[i][j], 0, 0, 0);
  }

  float bvals[4];
  #pragma unroll
  for (int j = 0; j < 4; ++j) bvals[j] = bias[n0 + wn + j * 16 + (lane & 15)];
  const int r0 = (lane >> 4) * 4;
  #pragma unroll
  for (int i = 0; i < 2; ++i) {
    #pragma unroll
    for (int r = 0; r < 4; ++r) {
      const int gm = m0 + wm + i * 16 + r0 + r;
      float* orow = out + (size_t)gm * 768 + n0 + wn;
      #pragma unroll
      for (int j = 0; j < 4; ++j)
        orow[j * 16 + (lane & 15)] = acc[i][j][r] + bvals[j];
    }
  }
}

extern "C" void kernel_launch(void* const* d_in, const int* in_sizes, int n_in,
                              void* d_out, int out_size, void* d_ws, size_t ws_size,
                              hipStream_t stream) {
  const int* token_ids       = (const int*)d_in[0];
  const int* segment_ids     = (const int*)d_in[1];
  const int* section_ids     = (const int*)d_in[2];
  const int* temporality_ids = (const int*)d_in[3];
  const int* negation_ids    = (const int*)d_in[4];
  const int* position_ids    = (const int*)d_in[5];
  const int* timestamp_ids   = (const int*)d_in[6];
  const float* token_table       = (const float*)d_in[7];
  const float* section_table     = (const float*)d_in[8];
  const float* temporality_table = (const float*)d_in[9];
  const float* negation_table    = (const float*)d_in[10];
  const float* position_table    = (const float*)d_in[11];
  const float* timestamp_table   = (const float*)d_in[12];
  const float* ln_gamma = (const float*)d_in[13];
  const float* ln_beta  = (const float*)d_in[14];
  const float* proj_w   = (const float*)d_in[15];
  const float* proj_b   = (const float*)d_in[16];

  float* out = (float*)d_out;
  bf16* wsW = (bf16*)d_ws;                        // 768*768 bf16   (1.18 MB)
  bf16* wsN = wsW + (size_t)Dn * Dn;              // 4096*768 bf16  (6.29 MB)
  int*  wsS = (int*)((char*)d_ws + (size_t)(Dn * Dn + NSEG * Dn) * 2);  // 4097 ints

  // W->bf16 (576) + mask zeros (16) + segment bounds (256)
  k_prep<<<848, 256, 0, stream>>>(proj_w, wsW, out + (size_t)NSEG * Dn,
                                  segment_ids, wsS);
  // pool + enrich + LN -> bf16 normed (one wave per segment)
  k_pool_ln<<<NSEG, 64, 0, stream>>>(token_ids, wsS, section_ids,
      temporality_ids, negation_ids, position_ids, timestamp_ids,
      token_table, section_table, temporality_table, negation_table,
      position_table, timestamp_table, ln_gamma, ln_beta, wsN);
  // projection GEMM + bias
  k_gemm<<<dim3(6, 64), 256, 0, stream>>>(wsN, wsW, proj_b, out);
}